// Round 11
// baseline (437.112 us; speedup 1.0000x reference)
//
#include <hip/hip_runtime.h>
#include <math.h>

#define NN 25000
#define NE 100000

typedef _Float16 f16;
typedef _Float16 half8 __attribute__((ext_vector_type(8)));
typedef float f32x4 __attribute__((ext_vector_type(4)));

// ---------------- one-time weight prep (merged) ----------------
__global__ __launch_bounds__(256) void prep_all(
    const float* __restrict__ Wn1, const float* __restrict__ Wn2,
    const float* __restrict__ Wn3, const float* __restrict__ We1,
    const float* __restrict__ We2, const float* __restrict__ Wih,
    const float* __restrict__ Whh, const float* __restrict__ We3,
    const float* __restrict__ be3, const float* __restrict__ roots,
    float* __restrict__ T, f16* __restrict__ Wf16, f16* __restrict__ root16,
    f16* __restrict__ Wih16, f16* __restrict__ Whh16)
{
    int f = blockIdx.x * 256 + threadIdx.x;          // 0 .. 318463
    if (f >= 318464) return;
    if (f < 15360) {
        if (f < 2048)       { int j = f;         T[f] = Wn1[(j & 63) * 32 + (j >> 6)]; }
        else if (f < 6144)  { int j = f - 2048;  T[f] = Wn2[(j & 63) * 64 + (j >> 6)]; }
        else if (f < 10240) { int j = f - 6144;  T[f] = Wn3[(j & 63) * 64 + (j >> 6)]; }
        else if (f < 11264) { int j = f - 10240; T[f] = We1[(j & 63) * 16 + (j >> 6)]; }
        else                { int j = f - 11264; T[f] = We2[(j & 63) * 64 + (j >> 6)]; }
    } else {
        int g = f - 15360;
        if (g < 266240) {
            if (g < 262144) Wf16[g] = (f16)We3[g];
            else {
                int j = g - 262144; int o = (j >> 6), k = j & 63;
                Wf16[g] = (f16)be3[k * 64 + o];
            }
        } else {
            int g2 = g - 266240;
            if (g2 < 12288) {                        // root16[l][o][i] = roots[l][i][o]
                int l = g2 >> 12, j = g2 & 4095, o = j >> 6, i = j & 63;
                root16[g2] = (f16)roots[l * 4096 + i * 64 + o];
            } else if (g2 < 24576) Wih16[g2 - 12288] = (f16)Wih[g2 - 12288];
            else                   Whh16[g2 - 24576] = (f16)Whh[g2 - 24576];
        }
    }
}

// ---------------- node MLP: 8 nodes per wave ----------------
__global__ __launch_bounds__(256) void node_mlp(
    const float* __restrict__ x, const float* __restrict__ T,
    const float* __restrict__ bn1, const float* __restrict__ bn2,
    const float* __restrict__ bn3,
    float* __restrict__ hbuf, f16* __restrict__ h16, float* __restrict__ aggr)
{
    __shared__ float sx[4][8][32];
    __shared__ float sh1[4][8][64];
    const float* Wn1T = T;            // [32][64]
    const float* Wn2T = T + 2048;     // [64][64]
    const float* Wn3T = T + 6144;     // [64][64]
    int w = threadIdx.x >> 6, lane = threadIdx.x & 63;
    int n0 = blockIdx.x * 32 + w * 8;
    if (n0 >= NN) return;             // NN%8==0
    #pragma unroll
    for (int jj = 0; jj < 4; ++jj) {
        int f = jj * 64 + lane;
        sx[w][f >> 5][f & 31] = x[(size_t)(n0 + (f >> 5)) * 32 + (f & 31)];
    }
    float a[8];
    #pragma unroll
    for (int j = 0; j < 8; ++j) a[j] = bn1[lane];
    for (int i = 0; i < 32; i += 4) {
        float4 bb[8];
        #pragma unroll
        for (int j = 0; j < 8; ++j) bb[j] = *(const float4*)&sx[w][j][i];
        #pragma unroll
        for (int ii = 0; ii < 4; ++ii) {
            float wv = Wn1T[(i + ii) * 64 + lane];
            #pragma unroll
            for (int j = 0; j < 8; ++j) a[j] += ((const float*)&bb[j])[ii] * wv;
        }
    }
    #pragma unroll
    for (int j = 0; j < 8; ++j) { sh1[w][j][lane] = fmaxf(a[j], 0.f); a[j] = bn2[lane]; }
    for (int i = 0; i < 64; i += 4) {
        float4 bb[8];
        #pragma unroll
        for (int j = 0; j < 8; ++j) bb[j] = *(const float4*)&sh1[w][j][i];
        #pragma unroll
        for (int ii = 0; ii < 4; ++ii) {
            float wv = Wn2T[(i + ii) * 64 + lane];
            #pragma unroll
            for (int j = 0; j < 8; ++j) a[j] += ((const float*)&bb[j])[ii] * wv;
        }
    }
    #pragma unroll
    for (int j = 0; j < 8; ++j) { sh1[w][j][lane] = fmaxf(a[j], 0.f); a[j] = bn3[lane]; }
    for (int i = 0; i < 64; i += 4) {
        float4 bb[8];
        #pragma unroll
        for (int j = 0; j < 8; ++j) bb[j] = *(const float4*)&sh1[w][j][i];
        #pragma unroll
        for (int ii = 0; ii < 4; ++ii) {
            float wv = Wn3T[(i + ii) * 64 + lane];
            #pragma unroll
            for (int j = 0; j < 8; ++j) a[j] += ((const float*)&bb[j])[ii] * wv;
        }
    }
    #pragma unroll
    for (int j = 0; j < 8; ++j) {
        size_t idx = (size_t)(n0 + j) * 64 + lane;
        hbuf[idx] = a[j];
        h16[idx]  = (f16)a[j];
        aggr[idx] = 0.f;
    }
}

// ---------------- edge MLP: 8 edges per wave ----------------
__global__ __launch_bounds__(256) void edge_mlp(
    const float* __restrict__ ea, const float* __restrict__ T,
    const float* __restrict__ be1, const float* __restrict__ be2,
    f16* __restrict__ ew16)
{
    __shared__ float sa[4][8][16];
    __shared__ float st[4][8][64];
    const float* We1T = T + 10240;    // [16][64]
    const float* We2T = T + 11264;    // [64][64]
    int w = threadIdx.x >> 6, lane = threadIdx.x & 63;
    int e0 = blockIdx.x * 32 + w * 8;
    if (e0 >= NE) return;
    #pragma unroll
    for (int jj = 0; jj < 2; ++jj) {
        int f = jj * 64 + lane;
        sa[w][f >> 4][f & 15] = ea[(size_t)(e0 + (f >> 4)) * 16 + (f & 15)];
    }
    float a[8];
    #pragma unroll
    for (int j = 0; j < 8; ++j) a[j] = be1[lane];
    for (int i = 0; i < 16; i += 4) {
        float4 bb[8];
        #pragma unroll
        for (int j = 0; j < 8; ++j) bb[j] = *(const float4*)&sa[w][j][i];
        #pragma unroll
        for (int ii = 0; ii < 4; ++ii) {
            float wv = We1T[(i + ii) * 64 + lane];
            #pragma unroll
            for (int j = 0; j < 8; ++j) a[j] += ((const float*)&bb[j])[ii] * wv;
        }
    }
    #pragma unroll
    for (int j = 0; j < 8; ++j) { st[w][j][lane] = fmaxf(a[j], 0.f); a[j] = be2[lane]; }
    for (int i = 0; i < 64; i += 4) {
        float4 bb[8];
        #pragma unroll
        for (int j = 0; j < 8; ++j) bb[j] = *(const float4*)&st[w][j][i];
        #pragma unroll
        for (int ii = 0; ii < 4; ++ii) {
            float wv = We2T[(i + ii) * 64 + lane];
            #pragma unroll
            for (int j = 0; j < 8; ++j) a[j] += ((const float*)&bb[j])[ii] * wv;
        }
    }
    #pragma unroll
    for (int j = 0; j < 8; ++j)
        ew16[(size_t)(e0 + j) * 64 + lane] = (f16)fmaxf(a[j], 0.f);
}

// ---------------- message GEMM (MFMA f16) + scatter ----------------
__device__ __forceinline__ half8 splat8(f16 v)
{ half8 r = { v, v, v, v, v, v, v, v }; return r; }

// N-SPLIT tiling: block = 128 edges, 4 waves; each wave computes ALL 128
// edges (8 M-subtiles) x its OWN 16-col quarter. Per slab per wave: 2 B-frag
// ds_reads (was 8) + 16 MFMA. RACE FIX vs round 10: the ev hoist reads ew
// rows staged by ALL waves -> it must sit BETWEEN two barriers (round 7-9's
// pre-barrier hoist was legal only because each wave read its own rows).
__global__ __launch_bounds__(256) void msg_mfma(
    const f16* __restrict__ h16, const f16* __restrict__ ew16,
    const f16* __restrict__ Wf16, const int* __restrict__ edge_index,
    float* __restrict__ aggr)
{
    __shared__ f16 sh_h[128][72];      // 18432 B
    __shared__ f16 sh_ring[4][4096];   // 32768 B: ew staging, then 4-slab B ring
    __shared__ int sh_dst[128];
    int t = threadIdx.x, lane = t & 63, wv = t >> 6;
    int e0 = blockIdx.x * 128;
    char* ringc = (char*)&sh_ring[0][0];

    const uint4* gW = (const uint4*)Wf16;            // 512 uint4 per 8KB slab
    uint4 r0 = gW[t], r1 = gW[256 + t], r2 = gW[512 + t], r3 = gW[768 + t];

    {   // gather 128 h-rows (padded) + 128 ew-rows (packed+swizzled into ring)
        int row = t >> 1, part = t & 1;
        int e = e0 + row;
        bool valid = e < NE;
        int ec = valid ? e : NE - 1;
        int src = edge_index[ec];
        const uint4* hp = (const uint4*)(h16 + (size_t)src * 64 + part * 32);
        const uint4* ep = (const uint4*)(ew16 + (size_t)ec * 64 + part * 32);
        uint4 z = make_uint4(0u, 0u, 0u, 0u);
        uint4 h0 = hp[0], h1 = hp[1], h2 = hp[2], h3 = hp[3];
        uint4 g0 = valid ? ep[0] : z;
        uint4 g1 = valid ? ep[1] : z;
        uint4 g2 = valid ? ep[2] : z;
        uint4 g3 = valid ? ep[3] : z;
        *(uint4*)&sh_h[row][part * 32]      = h0;
        *(uint4*)&sh_h[row][part * 32 + 8]  = h1;
        *(uint4*)&sh_h[row][part * 32 + 16] = h2;
        *(uint4*)&sh_h[row][part * 32 + 24] = h3;
        int rb = row * 128, key = (row & 7) << 4;
        *(uint4*)(ringc + rb + ((part * 64 +  0) ^ key)) = g0;
        *(uint4*)(ringc + rb + ((part * 64 + 16) ^ key)) = g1;
        *(uint4*)(ringc + rb + ((part * 64 + 32) ^ key)) = g2;
        *(uint4*)(ringc + rb + ((part * 64 + 48) ^ key)) = g3;
        if (lane < 32) {
            int e2 = e0 + wv * 32 + lane;
            sh_dst[wv * 32 + lane] = (e2 < NE) ? edge_index[NE + e2] : -1;
        }
    }
    __syncthreads();                  // RACE FIX: all ew rows staged before hoist

    int r16 = lane & 15, kq = lane >> 4;

    // K-invariant ew fragments for all 8 M-subtiles (rows m*16 + r16)
    half8 ev0[8], ev1[8];
    {
        int key = (r16 & 7) << 4;                    // (row&7) == (r16&7)
        #pragma unroll
        for (int m = 0; m < 8; ++m) {
            int row = m * 16 + r16;
            ev0[m] = *(const half8*)(ringc + row * 128 + ((kq * 16) ^ key));
            ev1[m] = *(const half8*)(ringc + row * 128 + ((64 + kq * 16) ^ key));
        }
    }

    __syncthreads();                  // hoists done, ring free for B staging

    int d0 = t * 16, d1 = 4096 + t * 16;
    int dsw0 = d0 ^ (((d0 >> 7) & 7) << 4);
    int dsw1 = d1 ^ (((d1 >> 7) & 7) << 4);

    *(uint4*)(ringc + dsw0) = r0;
    *(uint4*)(ringc + dsw1) = r1;
    *(uint4*)(ringc + 8192 + dsw0) = r2;
    *(uint4*)(ringc + 8192 + dsw1) = r3;
    r0 = gW[2 * 512 + t]; r1 = gW[2 * 512 + 256 + t];
    r2 = gW[3 * 512 + t]; r3 = gW[3 * 512 + 256 + t];
    __syncthreads();                  // pair0 ready

    f32x4 acc[8];
    #pragma unroll
    for (int m = 0; m < 8; ++m) acc[m] = (f32x4){0, 0, 0, 0};

    int swzA = (kq << 4) ^ ((r16 & 7) << 4);
    int swzB = ((kq << 4) | 64) ^ ((r16 & 7) << 4);
    int colBase = wv * 2048 + r16 * 128;             // wave's 16-col quarter

    for (int i8 = 0; i8 < 8; ++i8) {
        half8 hM[8];
        #pragma unroll
        for (int m = 0; m < 8; ++m)
            hM[m] = *(const half8*)&sh_h[m * 16 + r16][i8 * 8];
        #pragma unroll
        for (int w2 = 0; w2 < 4; ++w2) {
            const char* pairR = ringc + (w2 & 1) * 16384 + colBase;
            #pragma unroll
            for (int s = 0; s < 2; ++s) {
                const char* bb = pairR + s * 8192;
                half8 bs0 = *(const half8*)(bb + swzA);
                half8 bs1 = *(const half8*)(bb + swzB);
                #pragma unroll
                for (int m = 0; m < 8; ++m) {
                    f16 hs = hM[m][w2 * 2 + s];      // static index
                    half8 a0 = ev0[m] * splat8(hs);
                    half8 a1 = ev1[m] * splat8(hs);
                    acc[m] = __builtin_amdgcn_mfma_f32_16x16x32_f16(a0, bs0, acc[m], 0, 0, 0);
                    acc[m] = __builtin_amdgcn_mfma_f32_16x16x32_f16(a1, bs1, acc[m], 0, 0, 0);
                }
            }
            char* wb = ringc + ((w2 + 1) & 1) * 16384;
            *(uint4*)(wb + dsw0) = r0;
            *(uint4*)(wb + dsw1) = r1;
            *(uint4*)(wb + 8192 + dsw0) = r2;
            *(uint4*)(wb + 8192 + dsw1) = r3;
            int jw = i8 * 4 + w2;
            int sA = jw * 2 + 4; if (sA > 64) sA = 64;
            int sB = jw * 2 + 5; if (sB > 64) sB = 64;
            r0 = gW[(size_t)sA * 512 + t]; r1 = gW[(size_t)sA * 512 + 256 + t];
            r2 = gW[(size_t)sB * 512 + t]; r3 = gW[(size_t)sB * 512 + 256 + t];
            __syncthreads();
        }
    }

    {   // bias slab (64) in pair0 half0: A = h16 rows, B = be3T
        const char* bb = ringc + colBase;
        half8 bs0 = *(const half8*)(bb + swzA);
        half8 bs1 = *(const half8*)(bb + swzB);
        #pragma unroll
        for (int m = 0; m < 8; ++m) {
            int row = m * 16 + r16;
            half8 a0 = *(const half8*)&sh_h[row][kq * 8];
            half8 a1 = *(const half8*)&sh_h[row][32 + kq * 8];
            acc[m] = __builtin_amdgcn_mfma_f32_16x16x32_f16(a0, bs0, acc[m], 0, 0, 0);
            acc[m] = __builtin_amdgcn_mfma_f32_16x16x32_f16(a1, bs1, acc[m], 0, 0, 0);
        }
    }

    // scatter: D col (=r16) is the o-col within this wave's quarter;
    // D row = kq*4+reg is the edge-sub-row  [m89-verified layout]
    #pragma unroll
    for (int m = 0; m < 8; ++m) {
        #pragma unroll
        for (int reg = 0; reg < 4; ++reg) {
            int e_l = m * 16 + kq * 4 + reg;
            int d = sh_dst[e_l];
            if (d >= 0)
                atomicAdd(aggr + (size_t)d * 64 + wv * 16 + r16, acc[m][reg]);
        }
    }
}

// ---------------- fused GRU via MFMA: 1 wave / 16 nodes, no barriers ----------------
// Waves independent; LDS strictly wave-local (written and read by the same
// wave -> program order + compiler lgkmcnt suffice, no barrier needed).
__global__ __launch_bounds__(64) void gru_mfma(
    float* __restrict__ aggr, float* __restrict__ hbuf, f16* __restrict__ h16,
    const f16* __restrict__ root16, const float* __restrict__ cbias,
    const f16* __restrict__ Wih16, const f16* __restrict__ Whh16,
    const float* __restrict__ bih, const float* __restrict__ bhh,
    float* __restrict__ out2, int first)
{
    __shared__ f16 sh[16][72];     // h16 rows (A-frags for root & Whh GEMMs)
    __shared__ f16 sm[16][72];     // m rows (f16, A-frags for Wih GEMM)
    int lane = threadIdx.x & 63;
    int n0 = blockIdx.x * 16;

    {   // stage 16 h rows (masked tail -> zeros); wave-local
        int row = lane >> 2, part = lane & 3;
        int n = n0 + row;
        uint4 z = make_uint4(0u, 0u, 0u, 0u);
        const uint4* hp = (const uint4*)(h16 + (size_t)n * 64 + part * 16);
        uint4 v0 = (n < NN) ? hp[0] : z;
        uint4 v1 = (n < NN) ? hp[1] : z;
        *(uint4*)&sh[row][part * 16]     = v0;
        *(uint4*)&sh[row][part * 16 + 8] = v1;
    }

    int r16 = lane & 15, kq = lane >> 4;
    half8 ah0 = *(const half8*)&sh[r16][kq * 8];
    half8 ah1 = *(const half8*)&sh[r16][32 + kq * 8];
    int nodeBase = kq * 4;            // C/D row = kq*4 + reg

    // ---- m = aggr + cbias + h @ root^T ----
    f32x4 accm[4];
    #pragma unroll
    for (int tt = 0; tt < 4; ++tt) {
        int o = tt * 16 + r16;
        float cb = cbias[o];
        #pragma unroll
        for (int reg = 0; reg < 4; ++reg) {
            int n = n0 + nodeBase + reg;
            float v = 0.f;
            if (n < NN) {
                size_t ix = (size_t)n * 64 + o;
                v = aggr[ix] + cb;
                aggr[ix] = 0.f;       // ready for next layer's atomics
            }
            accm[tt][reg] = v;
        }
    }
    #pragma unroll
    for (int tt = 0; tt < 4; ++tt) {
        const f16* bp = root16 + (size_t)(tt * 16 + r16) * 64 + kq * 8;
        half8 b0 = *(const half8*)bp;
        half8 b1 = *(const half8*)(bp + 32);
        accm[tt] = __builtin_amdgcn_mfma_f32_16x16x32_f16(ah0, b0, accm[tt], 0, 0, 0);
        accm[tt] = __builtin_amdgcn_mfma_f32_16x16x32_f16(ah1, b1, accm[tt], 0, 0, 0);
    }
    #pragma unroll
    for (int tt = 0; tt < 4; ++tt)
        #pragma unroll
        for (int reg = 0; reg < 4; ++reg)
            sm[nodeBase + reg][tt * 16 + r16] = (f16)accm[tt][reg];
    half8 am0 = *(const half8*)&sm[r16][kq * 8];
    half8 am1 = *(const half8*)&sm[r16][32 + kq * 8];

    // ---- gate GEMMs ----
    f32x4 acc_rz[8], acc_in[4], acc_hn[4];
    #pragma unroll
    for (int tt = 0; tt < 8; ++tt) acc_rz[tt] = (f32x4){0, 0, 0, 0};
    #pragma unroll
    for (int tt = 0; tt < 4; ++tt) { acc_in[tt] = (f32x4){0, 0, 0, 0}; acc_hn[tt] = (f32x4){0, 0, 0, 0}; }

    #pragma unroll
    for (int tt = 0; tt < 8; ++tt) {          // r (o 0..63) / z (o 64..127): gi part
        const f16* bp = Wih16 + (size_t)(tt * 16 + r16) * 64 + kq * 8;
        half8 b0 = *(const half8*)bp;
        half8 b1 = *(const half8*)(bp + 32);
        acc_rz[tt] = __builtin_amdgcn_mfma_f32_16x16x32_f16(am0, b0, acc_rz[tt], 0, 0, 0);
        acc_rz[tt] = __builtin_amdgcn_mfma_f32_16x16x32_f16(am1, b1, acc_rz[tt], 0, 0, 0);
    }
    #pragma unroll
    for (int tt = 0; tt < 4; ++tt) {          // i_n (o 128..191)
        const f16* bp = Wih16 + (size_t)(128 + tt * 16 + r16) * 64 + kq * 8;
        half8 b0 = *(const half8*)bp;
        half8 b1 = *(const half8*)(bp + 32);
        acc_in[tt] = __builtin_amdgcn_mfma_f32_16x16x32_f16(am0, b0, acc_in[tt], 0, 0, 0);
        acc_in[tt] = __builtin_amdgcn_mfma_f32_16x16x32_f16(am1, b1, acc_in[tt], 0, 0, 0);
    }
    if (!first) {
        #pragma unroll
        for (int tt = 0; tt < 8; ++tt) {      // gh part sums into same r/z acc
            const f16* bp = Whh16 + (size_t)(tt * 16 + r16) * 64 + kq * 8;
            half8 b0 = *(const half8*)bp;
            half8 b1 = *(const half8*)(bp + 32);
            acc_rz[tt] = __builtin_amdgcn_mfma_f32_16x16x32_f16(ah0, b0, acc_rz[tt], 0, 0, 0);
            acc_rz[tt] = __builtin_amdgcn_mfma_f32_16x16x32_f16(ah1, b1, acc_rz[tt], 0, 0, 0);
        }
        #pragma unroll
        for (int tt = 0; tt < 4; ++tt) {      // h_n separate (r multiplies it)
            const f16* bp = Whh16 + (size_t)(128 + tt * 16 + r16) * 64 + kq * 8;
            half8 b0 = *(const half8*)bp;
            half8 b1 = *(const half8*)(bp + 32);
            acc_hn[tt] = __builtin_amdgcn_mfma_f32_16x16x32_f16(ah0, b0, acc_hn[tt], 0, 0, 0);
            acc_hn[tt] = __builtin_amdgcn_mfma_f32_16x16x32_f16(ah1, b1, acc_hn[tt], 0, 0, 0);
        }
    }

    // ---- gates + store ----
    #pragma unroll
    for (int tt = 0; tt < 4; ++tt) {
        int o = tt * 16 + r16;
        float b_r = bih[o] + bhh[o];
        float b_z = bih[64 + o] + bhh[64 + o];
        float bin = bih[128 + o];
        float bhn = bhh[128 + o];
        #pragma unroll
        for (int reg = 0; reg < 4; ++reg) {
            int n = n0 + nodeBase + reg;
            if (n >= NN) continue;
            size_t ix = (size_t)n * 64 + o;
            float rv = 1.f / (1.f + expf(-(acc_rz[tt][reg] + b_r)));
            float zv = 1.f / (1.f + expf(-(acc_rz[4 + tt][reg] + b_z)));
            float hn_ = first ? bhn : (acc_hn[tt][reg] + bhn);
            float nv = tanhf(acc_in[tt][reg] + bin + rv * hn_);
            float hold = first ? 0.f : hbuf[ix];
            float outv = (1.f - zv) * nv + zv * hold;
            hbuf[ix] = outv;
            h16[ix]  = (f16)outv;
            if (out2) out2[ix] = outv;
        }
    }
}

extern "C" void kernel_launch(void* const* d_in, const int* in_sizes, int n_in,
                              void* d_out, int out_size, void* d_ws, size_t ws_size,
                              hipStream_t stream)
{
    const float* x   = (const float*)d_in[0];
    const float* ea  = (const float*)d_in[1];
    const float* Wn1 = (const float*)d_in[2];  const float* bn1 = (const float*)d_in[3];
    const float* Wn2 = (const float*)d_in[4];  const float* bn2 = (const float*)d_in[5];
    const float* Wn3 = (const float*)d_in[6];  const float* bn3 = (const float*)d_in[7];
    const float* We1 = (const float*)d_in[8];  const float* be1 = (const float*)d_in[9];
    const float* We2 = (const float*)d_in[10]; const float* be2 = (const float*)d_in[11];
    const float* We3 = (const float*)d_in[12]; const float* be3 = (const float*)d_in[13];
    const float* roots = (const float*)d_in[14];
    const float* cb    = (const float*)d_in[15];
    const float* Wih = (const float*)d_in[16]; const float* Whh = (const float*)d_in[17];
    const float* bih = (const float*)d_in[18]; const float* bhh = (const float*)d_in[19];
    const int*   ei  = (const int*)d_in[20];

    // ws layout: fp32 region then fp16 region (16B-aligned)
    float* ws   = (float*)d_ws;
    float* hbuf = ws;                               // N*64
    float* aggr = hbuf + (size_t)NN * 64;           // N*64
    float* Tbuf = aggr + (size_t)NN * 64;           // 15360 (pad to 16384)
    f16*   h16  = (f16*)(ws + 2 * (size_t)NN * 64 + 16384);   // N*64
    f16*   ew16 = h16  + (size_t)NN * 64;                     // E*64
    f16*   Wf16 = ew16 + (size_t)NE * 64;                     // 266240
    f16*   root16 = Wf16 + 266240;                            // 3*4096
    f16*   Wih16  = root16 + 12288;                           // 192*64
    f16*   Whh16  = Wih16 + 12288;                            // 192*64

    prep_all<<<(318464 + 255) / 256, 256, 0, stream>>>(Wn1, Wn2, Wn3, We1, We2,
        Wih, Whh, We3, be3, roots, Tbuf, Wf16, root16, Wih16, Whh16);
    node_mlp<<<(NN + 31) / 32, 256, 0, stream>>>(x, Tbuf, bn1, bn2, bn3,
                                                 hbuf, h16, aggr);
    edge_mlp<<<NE / 32, 256, 0, stream>>>(ea, Tbuf, be1, be2, ew16);

    for (int l = 0; l < 3; ++l) {
        msg_mfma<<<(NE + 127) / 128, 256, 0, stream>>>(h16, ew16, Wf16, ei, aggr);
        gru_mfma<<<(NN + 15) / 16, 64, 0, stream>>>(aggr, hbuf, h16,
            root16 + (size_t)l * 4096, cb + (size_t)l * 64,
            Wih16, Whh16, bih, bhh,
            (l == 2) ? (float*)d_out : nullptr, (l == 0) ? 1 : 0);
    }
}

// Round 12
// 400.807 us; speedup vs baseline: 1.0906x; 1.0906x over previous
//
#include <hip/hip_runtime.h>
#include <math.h>

#define NN 25000
#define NE 100000

typedef _Float16 f16;
typedef _Float16 half8 __attribute__((ext_vector_type(8)));
typedef float f32x4 __attribute__((ext_vector_type(4)));

// ---------------- one-time weight prep (merged) ----------------
__global__ __launch_bounds__(256) void prep_all(
    const float* __restrict__ Wn1, const float* __restrict__ Wn2,
    const float* __restrict__ Wn3, const float* __restrict__ We1,
    const float* __restrict__ We2, const float* __restrict__ Wih,
    const float* __restrict__ Whh, const float* __restrict__ We3,
    const float* __restrict__ be3, const float* __restrict__ roots,
    float* __restrict__ T, f16* __restrict__ Wf16, f16* __restrict__ root16,
    f16* __restrict__ Wih16, f16* __restrict__ Whh16)
{
    int f = blockIdx.x * 256 + threadIdx.x;          // 0 .. 318463
    if (f >= 318464) return;
    if (f < 15360) {
        if (f < 2048)       { int j = f;         T[f] = Wn1[(j & 63) * 32 + (j >> 6)]; }
        else if (f < 6144)  { int j = f - 2048;  T[f] = Wn2[(j & 63) * 64 + (j >> 6)]; }
        else if (f < 10240) { int j = f - 6144;  T[f] = Wn3[(j & 63) * 64 + (j >> 6)]; }
        else if (f < 11264) { int j = f - 10240; T[f] = We1[(j & 63) * 16 + (j >> 6)]; }
        else                { int j = f - 11264; T[f] = We2[(j & 63) * 64 + (j >> 6)]; }
    } else {
        int g = f - 15360;
        if (g < 266240) {
            if (g < 262144) Wf16[g] = (f16)We3[g];
            else {
                int j = g - 262144; int o = (j >> 6), k = j & 63;
                Wf16[g] = (f16)be3[k * 64 + o];
            }
        } else {
            int g2 = g - 266240;
            if (g2 < 12288) {                        // root16[l][o][i] = roots[l][i][o]
                int l = g2 >> 12, j = g2 & 4095, o = j >> 6, i = j & 63;
                root16[g2] = (f16)roots[l * 4096 + i * 64 + o];
            } else if (g2 < 24576) Wih16[g2 - 12288] = (f16)Wih[g2 - 12288];
            else                   Whh16[g2 - 24576] = (f16)Whh[g2 - 24576];
        }
    }
}

// ---------------- node MLP: 8 nodes per wave ----------------
__global__ __launch_bounds__(256) void node_mlp(
    const float* __restrict__ x, const float* __restrict__ T,
    const float* __restrict__ bn1, const float* __restrict__ bn2,
    const float* __restrict__ bn3,
    float* __restrict__ hbuf, f16* __restrict__ h16, float* __restrict__ aggr)
{
    __shared__ float sx[4][8][32];
    __shared__ float sh1[4][8][64];
    const float* Wn1T = T;            // [32][64]
    const float* Wn2T = T + 2048;     // [64][64]
    const float* Wn3T = T + 6144;     // [64][64]
    int w = threadIdx.x >> 6, lane = threadIdx.x & 63;
    int n0 = blockIdx.x * 32 + w * 8;
    if (n0 >= NN) return;             // NN%8==0
    #pragma unroll
    for (int jj = 0; jj < 4; ++jj) {
        int f = jj * 64 + lane;
        sx[w][f >> 5][f & 31] = x[(size_t)(n0 + (f >> 5)) * 32 + (f & 31)];
    }
    float a[8];
    #pragma unroll
    for (int j = 0; j < 8; ++j) a[j] = bn1[lane];
    for (int i = 0; i < 32; i += 4) {
        float4 bb[8];
        #pragma unroll
        for (int j = 0; j < 8; ++j) bb[j] = *(const float4*)&sx[w][j][i];
        #pragma unroll
        for (int ii = 0; ii < 4; ++ii) {
            float wv = Wn1T[(i + ii) * 64 + lane];
            #pragma unroll
            for (int j = 0; j < 8; ++j) a[j] += ((const float*)&bb[j])[ii] * wv;
        }
    }
    #pragma unroll
    for (int j = 0; j < 8; ++j) { sh1[w][j][lane] = fmaxf(a[j], 0.f); a[j] = bn2[lane]; }
    for (int i = 0; i < 64; i += 4) {
        float4 bb[8];
        #pragma unroll
        for (int j = 0; j < 8; ++j) bb[j] = *(const float4*)&sh1[w][j][i];
        #pragma unroll
        for (int ii = 0; ii < 4; ++ii) {
            float wv = Wn2T[(i + ii) * 64 + lane];
            #pragma unroll
            for (int j = 0; j < 8; ++j) a[j] += ((const float*)&bb[j])[ii] * wv;
        }
    }
    #pragma unroll
    for (int j = 0; j < 8; ++j) { sh1[w][j][lane] = fmaxf(a[j], 0.f); a[j] = bn3[lane]; }
    for (int i = 0; i < 64; i += 4) {
        float4 bb[8];
        #pragma unroll
        for (int j = 0; j < 8; ++j) bb[j] = *(const float4*)&sh1[w][j][i];
        #pragma unroll
        for (int ii = 0; ii < 4; ++ii) {
            float wv = Wn3T[(i + ii) * 64 + lane];
            #pragma unroll
            for (int j = 0; j < 8; ++j) a[j] += ((const float*)&bb[j])[ii] * wv;
        }
    }
    #pragma unroll
    for (int j = 0; j < 8; ++j) {
        size_t idx = (size_t)(n0 + j) * 64 + lane;
        hbuf[idx] = a[j];
        h16[idx]  = (f16)a[j];
        aggr[idx] = 0.f;
    }
}

// ---------------- edge MLP: 8 edges per wave ----------------
__global__ __launch_bounds__(256) void edge_mlp(
    const float* __restrict__ ea, const float* __restrict__ T,
    const float* __restrict__ be1, const float* __restrict__ be2,
    f16* __restrict__ ew16)
{
    __shared__ float sa[4][8][16];
    __shared__ float st[4][8][64];
    const float* We1T = T + 10240;    // [16][64]
    const float* We2T = T + 11264;    // [64][64]
    int w = threadIdx.x >> 6, lane = threadIdx.x & 63;
    int e0 = blockIdx.x * 32 + w * 8;
    if (e0 >= NE) return;
    #pragma unroll
    for (int jj = 0; jj < 2; ++jj) {
        int f = jj * 64 + lane;
        sa[w][f >> 4][f & 15] = ea[(size_t)(e0 + (f >> 4)) * 16 + (f & 15)];
    }
    float a[8];
    #pragma unroll
    for (int j = 0; j < 8; ++j) a[j] = be1[lane];
    for (int i = 0; i < 16; i += 4) {
        float4 bb[8];
        #pragma unroll
        for (int j = 0; j < 8; ++j) bb[j] = *(const float4*)&sa[w][j][i];
        #pragma unroll
        for (int ii = 0; ii < 4; ++ii) {
            float wv = We1T[(i + ii) * 64 + lane];
            #pragma unroll
            for (int j = 0; j < 8; ++j) a[j] += ((const float*)&bb[j])[ii] * wv;
        }
    }
    #pragma unroll
    for (int j = 0; j < 8; ++j) { st[w][j][lane] = fmaxf(a[j], 0.f); a[j] = be2[lane]; }
    for (int i = 0; i < 64; i += 4) {
        float4 bb[8];
        #pragma unroll
        for (int j = 0; j < 8; ++j) bb[j] = *(const float4*)&st[w][j][i];
        #pragma unroll
        for (int ii = 0; ii < 4; ++ii) {
            float wv = We2T[(i + ii) * 64 + lane];
            #pragma unroll
            for (int j = 0; j < 8; ++j) a[j] += ((const float*)&bb[j])[ii] * wv;
        }
    }
    #pragma unroll
    for (int j = 0; j < 8; ++j)
        ew16[(size_t)(e0 + j) * 64 + lane] = (f16)fmaxf(a[j], 0.f);
}

// ---------------- message GEMM (MFMA f16) + scatter — round-9 proven version ----------------
__device__ __forceinline__ half8 splat8(f16 v)
{ half8 r = { v, v, v, v, v, v, v, v }; return r; }

__device__ __forceinline__ void mfma_block(
    const char* bb, int swzA, int swzB,
    half8 aA0, half8 aA1, half8 aB0, half8 aB1, f32x4 (&acc)[2][4])
{
    half8 b00 = *(const half8*)(bb + 0    + swzA);
    half8 b01 = *(const half8*)(bb + 0    + swzB);
    half8 b10 = *(const half8*)(bb + 2048 + swzA);
    half8 b11 = *(const half8*)(bb + 2048 + swzB);
    half8 b20 = *(const half8*)(bb + 4096 + swzA);
    half8 b21 = *(const half8*)(bb + 4096 + swzB);
    half8 b30 = *(const half8*)(bb + 6144 + swzA);
    half8 b31 = *(const half8*)(bb + 6144 + swzB);
    acc[0][0] = __builtin_amdgcn_mfma_f32_16x16x32_f16(aA0, b00, acc[0][0], 0, 0, 0);
    acc[0][0] = __builtin_amdgcn_mfma_f32_16x16x32_f16(aA1, b01, acc[0][0], 0, 0, 0);
    acc[0][1] = __builtin_amdgcn_mfma_f32_16x16x32_f16(aA0, b10, acc[0][1], 0, 0, 0);
    acc[0][1] = __builtin_amdgcn_mfma_f32_16x16x32_f16(aA1, b11, acc[0][1], 0, 0, 0);
    acc[0][2] = __builtin_amdgcn_mfma_f32_16x16x32_f16(aA0, b20, acc[0][2], 0, 0, 0);
    acc[0][2] = __builtin_amdgcn_mfma_f32_16x16x32_f16(aA1, b21, acc[0][2], 0, 0, 0);
    acc[0][3] = __builtin_amdgcn_mfma_f32_16x16x32_f16(aA0, b30, acc[0][3], 0, 0, 0);
    acc[0][3] = __builtin_amdgcn_mfma_f32_16x16x32_f16(aA1, b31, acc[0][3], 0, 0, 0);
    acc[1][0] = __builtin_amdgcn_mfma_f32_16x16x32_f16(aB0, b00, acc[1][0], 0, 0, 0);
    acc[1][0] = __builtin_amdgcn_mfma_f32_16x16x32_f16(aB1, b01, acc[1][0], 0, 0, 0);
    acc[1][1] = __builtin_amdgcn_mfma_f32_16x16x32_f16(aB0, b10, acc[1][1], 0, 0, 0);
    acc[1][1] = __builtin_amdgcn_mfma_f32_16x16x32_f16(aB1, b11, acc[1][1], 0, 0, 0);
    acc[1][2] = __builtin_amdgcn_mfma_f32_16x16x32_f16(aB0, b20, acc[1][2], 0, 0, 0);
    acc[1][2] = __builtin_amdgcn_mfma_f32_16x16x32_f16(aB1, b21, acc[1][2], 0, 0, 0);
    acc[1][3] = __builtin_amdgcn_mfma_f32_16x16x32_f16(aB0, b30, acc[1][3], 0, 0, 0);
    acc[1][3] = __builtin_amdgcn_mfma_f32_16x16x32_f16(aB1, b31, acc[1][3], 0, 0, 0);
}

// 4 waves x 32 edges (2 M-subtiles) — measured 70us / 31% MfmaUtil (R9).
// R8 lesson: don't trade occupancy for per-wave intensity (M=64, 2-wave: -2.4x).
// R11 lesson: don't N-split (A-build VALU duplicated 4x: 87us). This balance
// is a verified local optimum along the tiling axis.
// Pre-barrier ev hoist is legal HERE: each wave reads only rows its own
// lanes staged (t=2*row => wave(row>>5)); N-split variants MUST barrier first.
__global__ __launch_bounds__(256) void msg_mfma(
    const f16* __restrict__ h16, const f16* __restrict__ ew16,
    const f16* __restrict__ Wf16, const int* __restrict__ edge_index,
    float* __restrict__ aggr)
{
    __shared__ f16 sh_h[128][72];      // 18432 B
    __shared__ f16 sh_ring[4][4096];   // 32768 B: ew staging, then 4-slab B ring
    __shared__ int sh_dst[128];
    int t = threadIdx.x, lane = t & 63, wv = t >> 6;
    int e0 = blockIdx.x * 128;
    char* ringc = (char*)&sh_ring[0][0];

    const uint4* gW = (const uint4*)Wf16;            // 512 uint4 per 8KB slab
    uint4 r0 = gW[t], r1 = gW[256 + t], r2 = gW[512 + t], r3 = gW[768 + t];

    {   // gather 128 h-rows (padded) + 128 ew-rows (packed+swizzled into ring)
        int row = t >> 1, part = t & 1;
        int e = e0 + row;
        bool valid = e < NE;
        int ec = valid ? e : NE - 1;
        int src = edge_index[ec];
        const uint4* hp = (const uint4*)(h16 + (size_t)src * 64 + part * 32);
        const uint4* ep = (const uint4*)(ew16 + (size_t)ec * 64 + part * 32);
        uint4 z = make_uint4(0u, 0u, 0u, 0u);
        uint4 h0 = hp[0], h1 = hp[1], h2 = hp[2], h3 = hp[3];
        uint4 g0 = valid ? ep[0] : z;
        uint4 g1 = valid ? ep[1] : z;
        uint4 g2 = valid ? ep[2] : z;
        uint4 g3 = valid ? ep[3] : z;
        *(uint4*)&sh_h[row][part * 32]      = h0;
        *(uint4*)&sh_h[row][part * 32 + 8]  = h1;
        *(uint4*)&sh_h[row][part * 32 + 16] = h2;
        *(uint4*)&sh_h[row][part * 32 + 24] = h3;
        int rb = row * 128, key = (row & 7) << 4;
        *(uint4*)(ringc + rb + ((part * 64 +  0) ^ key)) = g0;
        *(uint4*)(ringc + rb + ((part * 64 + 16) ^ key)) = g1;
        *(uint4*)(ringc + rb + ((part * 64 + 32) ^ key)) = g2;
        *(uint4*)(ringc + rb + ((part * 64 + 48) ^ key)) = g3;
        if (lane < 32) {
            int e2 = e0 + wv * 32 + lane;
            sh_dst[wv * 32 + lane] = (e2 < NE) ? edge_index[NE + e2] : -1;
        }
    }

    int r16 = lane & 15, kq = lane >> 4;
    int row0 = wv * 32 + r16, row1 = row0 + 16;

    // wave-local hoist of K-invariant ew fragments (reads wave's own rows)
    int k0 = (row0 & 7) << 4, k1 = (row1 & 7) << 4;
    half8 evA0 = *(const half8*)(ringc + row0 * 128 + ((kq * 16) ^ k0));
    half8 evA1 = *(const half8*)(ringc + row0 * 128 + ((64 + kq * 16) ^ k0));
    half8 evB0 = *(const half8*)(ringc + row1 * 128 + ((kq * 16) ^ k1));
    half8 evB1 = *(const half8*)(ringc + row1 * 128 + ((64 + kq * 16) ^ k1));

    __syncthreads();                  // hoists done, ring free, dst visible

    int d0 = t * 16, d1 = 4096 + t * 16;
    int dsw0 = d0 ^ (((d0 >> 7) & 7) << 4);
    int dsw1 = d1 ^ (((d1 >> 7) & 7) << 4);

    *(uint4*)(ringc + dsw0) = r0;
    *(uint4*)(ringc + dsw1) = r1;
    *(uint4*)(ringc + 8192 + dsw0) = r2;
    *(uint4*)(ringc + 8192 + dsw1) = r3;
    r0 = gW[2 * 512 + t]; r1 = gW[2 * 512 + 256 + t];
    r2 = gW[3 * 512 + t]; r3 = gW[3 * 512 + 256 + t];
    __syncthreads();                  // pair0 ready

    f32x4 acc[2][4];
    #pragma unroll
    for (int m = 0; m < 2; ++m)
        #pragma unroll
        for (int n = 0; n < 4; ++n) acc[m][n] = (f32x4){0, 0, 0, 0};

    int swzA = (kq << 4) ^ ((r16 & 7) << 4);
    int swzB = ((kq << 4) | 64) ^ ((r16 & 7) << 4);

    for (int i8 = 0; i8 < 8; ++i8) {
        half8 hA = *(const half8*)&sh_h[row0][i8 * 8];
        half8 hB = *(const half8*)&sh_h[row1][i8 * 8];
        #pragma unroll
        for (int w2 = 0; w2 < 4; ++w2) {
            const char* pairR = ringc + (w2 & 1) * 16384 + r16 * 128;
            #pragma unroll
            for (int s = 0; s < 2; ++s) {
                f16 hsA = hA[w2 * 2 + s];
                f16 hsB = hB[w2 * 2 + s];
                mfma_block(pairR + s * 8192, swzA, swzB,
                           evA0 * splat8(hsA), evA1 * splat8(hsA),
                           evB0 * splat8(hsB), evB1 * splat8(hsB), acc);
            }
            char* wb = ringc + ((w2 + 1) & 1) * 16384;
            *(uint4*)(wb + dsw0) = r0;
            *(uint4*)(wb + dsw1) = r1;
            *(uint4*)(wb + 8192 + dsw0) = r2;
            *(uint4*)(wb + 8192 + dsw1) = r3;
            int jw = i8 * 4 + w2;
            int sA = jw * 2 + 4; if (sA > 64) sA = 64;
            int sB = jw * 2 + 5; if (sB > 64) sB = 64;
            r0 = gW[(size_t)sA * 512 + t]; r1 = gW[(size_t)sA * 512 + 256 + t];
            r2 = gW[(size_t)sB * 512 + t]; r3 = gW[(size_t)sB * 512 + 256 + t];
            __syncthreads();
        }
    }

    {   // bias slab (64): A = h16 rows, B = be3T
        const char* bb = ringc + r16 * 128;
        half8 aA0 = *(const half8*)&sh_h[row0][kq * 8];
        half8 aA1 = *(const half8*)&sh_h[row0][32 + kq * 8];
        half8 aB0 = *(const half8*)&sh_h[row1][kq * 8];
        half8 aB1 = *(const half8*)&sh_h[row1][32 + kq * 8];
        mfma_block(bb, swzA, swzB, aA0, aA1, aB0, aB1, acc);
    }

    // scatter: C/D layout col=lane&15, row=(lane>>4)*4+reg  [m89-verified]
    #pragma unroll
    for (int m = 0; m < 2; ++m) {
        #pragma unroll
        for (int reg = 0; reg < 4; ++reg) {
            int e_l = wv * 32 + m * 16 + kq * 4 + reg;
            int d = sh_dst[e_l];
            if (d >= 0) {
                float* ap = aggr + (size_t)d * 64 + r16;
                atomicAdd(ap,      acc[m][0][reg]);
                atomicAdd(ap + 16, acc[m][1][reg]);
                atomicAdd(ap + 32, acc[m][2][reg]);
                atomicAdd(ap + 48, acc[m][3][reg]);
            }
        }
    }
}

// ---------------- fused GRU via MFMA: 1 wave / 16 nodes, no barriers ----------------
// Waves independent; LDS strictly wave-local (same wave writes and reads ->
// program order + compiler lgkmcnt suffice). ~1563 blocks hide latency by TLP.
__global__ __launch_bounds__(64) void gru_mfma(
    float* __restrict__ aggr, float* __restrict__ hbuf, f16* __restrict__ h16,
    const f16* __restrict__ root16, const float* __restrict__ cbias,
    const f16* __restrict__ Wih16, const f16* __restrict__ Whh16,
    const float* __restrict__ bih, const float* __restrict__ bhh,
    float* __restrict__ out2, int first)
{
    __shared__ f16 sh[16][72];     // h16 rows (A-frags for root & Whh GEMMs)
    __shared__ f16 sm[16][72];     // m rows (f16, A-frags for Wih GEMM)
    int lane = threadIdx.x & 63;
    int n0 = blockIdx.x * 16;

    {   // stage 16 h rows (masked tail -> zeros); wave-local
        int row = lane >> 2, part = lane & 3;
        int n = n0 + row;
        uint4 z = make_uint4(0u, 0u, 0u, 0u);
        const uint4* hp = (const uint4*)(h16 + (size_t)n * 64 + part * 16);
        uint4 v0 = (n < NN) ? hp[0] : z;
        uint4 v1 = (n < NN) ? hp[1] : z;
        *(uint4*)&sh[row][part * 16]     = v0;
        *(uint4*)&sh[row][part * 16 + 8] = v1;
    }

    int r16 = lane & 15, kq = lane >> 4;
    half8 ah0 = *(const half8*)&sh[r16][kq * 8];
    half8 ah1 = *(const half8*)&sh[r16][32 + kq * 8];
    int nodeBase = kq * 4;            // C/D row = kq*4 + reg

    // ---- m = aggr + cbias + h @ root^T ----
    f32x4 accm[4];
    #pragma unroll
    for (int tt = 0; tt < 4; ++tt) {
        int o = tt * 16 + r16;
        float cb = cbias[o];
        #pragma unroll
        for (int reg = 0; reg < 4; ++reg) {
            int n = n0 + nodeBase + reg;
            float v = 0.f;
            if (n < NN) {
                size_t ix = (size_t)n * 64 + o;
                v = aggr[ix] + cb;
                aggr[ix] = 0.f;       // ready for next layer's atomics
            }
            accm[tt][reg] = v;
        }
    }
    #pragma unroll
    for (int tt = 0; tt < 4; ++tt) {
        const f16* bp = root16 + (size_t)(tt * 16 + r16) * 64 + kq * 8;
        half8 b0 = *(const half8*)bp;
        half8 b1 = *(const half8*)(bp + 32);
        accm[tt] = __builtin_amdgcn_mfma_f32_16x16x32_f16(ah0, b0, accm[tt], 0, 0, 0);
        accm[tt] = __builtin_amdgcn_mfma_f32_16x16x32_f16(ah1, b1, accm[tt], 0, 0, 0);
    }
    #pragma unroll
    for (int tt = 0; tt < 4; ++tt)
        #pragma unroll
        for (int reg = 0; reg < 4; ++reg)
            sm[nodeBase + reg][tt * 16 + r16] = (f16)accm[tt][reg];
    half8 am0 = *(const half8*)&sm[r16][kq * 8];
    half8 am1 = *(const half8*)&sm[r16][32 + kq * 8];

    // ---- gate GEMMs ----
    f32x4 acc_rz[8], acc_in[4], acc_hn[4];
    #pragma unroll
    for (int tt = 0; tt < 8; ++tt) acc_rz[tt] = (f32x4){0, 0, 0, 0};
    #pragma unroll
    for (int tt = 0; tt < 4; ++tt) { acc_in[tt] = (f32x4){0, 0, 0, 0}; acc_hn[tt] = (f32x4){0, 0, 0, 0}; }

    #pragma unroll
    for (int tt = 0; tt < 8; ++tt) {          // r (o 0..63) / z (o 64..127): gi part
        const f16* bp = Wih16 + (size_t)(tt * 16 + r16) * 64 + kq * 8;
        half8 b0 = *(const half8*)bp;
        half8 b1 = *(const half8*)(bp + 32);
        acc_rz[tt] = __builtin_amdgcn_mfma_f32_16x16x32_f16(am0, b0, acc_rz[tt], 0, 0, 0);
        acc_rz[tt] = __builtin_amdgcn_mfma_f32_16x16x32_f16(am1, b1, acc_rz[tt], 0, 0, 0);
    }
    #pragma unroll
    for (int tt = 0; tt < 4; ++tt) {          // i_n (o 128..191)
        const f16* bp = Wih16 + (size_t)(128 + tt * 16 + r16) * 64 + kq * 8;
        half8 b0 = *(const half8*)bp;
        half8 b1 = *(const half8*)(bp + 32);
        acc_in[tt] = __builtin_amdgcn_mfma_f32_16x16x32_f16(am0, b0, acc_in[tt], 0, 0, 0);
        acc_in[tt] = __builtin_amdgcn_mfma_f32_16x16x32_f16(am1, b1, acc_in[tt], 0, 0, 0);
    }
    if (!first) {
        #pragma unroll
        for (int tt = 0; tt < 8; ++tt) {      // gh part sums into same r/z acc
            const f16* bp = Whh16 + (size_t)(tt * 16 + r16) * 64 + kq * 8;
            half8 b0 = *(const half8*)bp;
            half8 b1 = *(const half8*)(bp + 32);
            acc_rz[tt] = __builtin_amdgcn_mfma_f32_16x16x32_f16(ah0, b0, acc_rz[tt], 0, 0, 0);
            acc_rz[tt] = __builtin_amdgcn_mfma_f32_16x16x32_f16(ah1, b1, acc_rz[tt], 0, 0, 0);
        }
        #pragma unroll
        for (int tt = 0; tt < 4; ++tt) {      // h_n separate (r multiplies it)
            const f16* bp = Whh16 + (size_t)(128 + tt * 16 + r16) * 64 + kq * 8;
            half8 b0 = *(const half8*)bp;
            half8 b1 = *(const half8*)(bp + 32);
            acc_hn[tt] = __builtin_amdgcn_mfma_f32_16x16x32_f16(ah0, b0, acc_hn[tt], 0, 0, 0);
            acc_hn[tt] = __builtin_amdgcn_mfma_f32_16x16x32_f16(ah1, b1, acc_hn[tt], 0, 0, 0);
        }
    }

    // ---- gates + store ----
    #pragma unroll
    for (int tt = 0; tt < 4; ++tt) {
        int o = tt * 16 + r16;
        float b_r = bih[o] + bhh[o];
        float b_z = bih[64 + o] + bhh[64 + o];
        float bin = bih[128 + o];
        float bhn = bhh[128 + o];
        #pragma unroll
        for (int reg = 0; reg < 4; ++reg) {
            int n = n0 + nodeBase + reg;
            if (n >= NN) continue;
            size_t ix = (size_t)n * 64 + o;
            float rv = 1.f / (1.f + expf(-(acc_rz[tt][reg] + b_r)));
            float zv = 1.f / (1.f + expf(-(acc_rz[4 + tt][reg] + b_z)));
            float hn_ = first ? bhn : (acc_hn[tt][reg] + bhn);
            float nv = tanhf(acc_in[tt][reg] + bin + rv * hn_);
            float hold = first ? 0.f : hbuf[ix];
            float outv = (1.f - zv) * nv + zv * hold;
            hbuf[ix] = outv;
            h16[ix]  = (f16)outv;
            if (out2) out2[ix] = outv;
        }
    }
}

extern "C" void kernel_launch(void* const* d_in, const int* in_sizes, int n_in,
                              void* d_out, int out_size, void* d_ws, size_t ws_size,
                              hipStream_t stream)
{
    const float* x   = (const float*)d_in[0];
    const float* ea  = (const float*)d_in[1];
    const float* Wn1 = (const float*)d_in[2];  const float* bn1 = (const float*)d_in[3];
    const float* Wn2 = (const float*)d_in[4];  const float* bn2 = (const float*)d_in[5];
    const float* Wn3 = (const float*)d_in[6];  const float* bn3 = (const float*)d_in[7];
    const float* We1 = (const float*)d_in[8];  const float* be1 = (const float*)d_in[9];
    const float* We2 = (const float*)d_in[10]; const float* be2 = (const float*)d_in[11];
    const float* We3 = (const float*)d_in[12]; const float* be3 = (const float*)d_in[13];
    const float* roots = (const float*)d_in[14];
    const float* cb    = (const float*)d_in[15];
    const float* Wih = (const float*)d_in[16]; const float* Whh = (const float*)d_in[17];
    const float* bih = (const float*)d_in[18]; const float* bhh = (const float*)d_in[19];
    const int*   ei  = (const int*)d_in[20];

    // ws layout: fp32 region then fp16 region (16B-aligned)
    float* ws   = (float*)d_ws;
    float* hbuf = ws;                               // N*64
    float* aggr = hbuf + (size_t)NN * 64;           // N*64
    float* Tbuf = aggr + (size_t)NN * 64;           // 15360 (pad to 16384)
    f16*   h16  = (f16*)(ws + 2 * (size_t)NN * 64 + 16384);   // N*64
    f16*   ew16 = h16  + (size_t)NN * 64;                     // E*64
    f16*   Wf16 = ew16 + (size_t)NE * 64;                     // 266240
    f16*   root16 = Wf16 + 266240;                            // 3*4096
    f16*   Wih16  = root16 + 12288;                           // 192*64
    f16*   Whh16  = Wih16 + 12288;                            // 192*64

    prep_all<<<(318464 + 255) / 256, 256, 0, stream>>>(Wn1, Wn2, Wn3, We1, We2,
        Wih, Whh, We3, be3, roots, Tbuf, Wf16, root16, Wih16, Whh16);
    node_mlp<<<(NN + 31) / 32, 256, 0, stream>>>(x, Tbuf, bn1, bn2, bn3,
                                                 hbuf, h16, aggr);
    edge_mlp<<<NE / 32, 256, 0, stream>>>(ea, Tbuf, be1, be2, ew16);

    for (int l = 0; l < 3; ++l) {
        msg_mfma<<<(NE + 127) / 128, 256, 0, stream>>>(h16, ew16, Wf16, ei, aggr);
        gru_mfma<<<(NN + 15) / 16, 64, 0, stream>>>(aggr, hbuf, h16,
            root16 + (size_t)l * 4096, cb + (size_t)l * 64,
            Wih16, Whh16, bih, bhh,
            (l == 2) ? (float*)d_out : nullptr, (l == 0) ? 1 : 0);
    }
}